// Round 2
// baseline (5228.793 us; speedup 1.0000x reference)
//
#include <hip/hip_runtime.h>
#include <cmath>

// ---------------------------------------------------------------------------
// BertBiLSTMCRF: em=(32,512,9) fp32, loss scalar, preds=(32,512) as float.
// Round 2 resubmit (round 1 hit "container failed twice" infra error; source
// unchanged — establishing the fp32 correctness-first baseline).
//   prep      : transpose w_ih -> [768][2048], w_hh -> [2][256][1024]; zero loss
//   gemm_x    : xpart[t*32+b][2048] = x @ w_ihT + bias   (fp32 VALU, 128x128 tile)
//   lstm_scan : 64 blocks = (dir,batch); 512 sequential steps, no grid sync
//   emissions : hcat(32,512,512) @ w_tag.T + b_tag -> d_out em
//   crf_fwd   : numerator + logsumexp scan -> loss (atomicAdd)
//   crf_viterbi: max/argmax scan + backtrack -> preds
// Workspace: ~176.2 MB fp32.
// ---------------------------------------------------------------------------

#define NB 32
#define NT 512
#define ND 768
#define NH 256
#define NG 1024   // 4*NH
#define NC 2048   // 2*NG
#define NL 9
#define NHC 512   // 2*NH

static const size_t OFF_WIHT  = 0;                       // 768*2048   = 1572864 floats
static const size_t OFF_WHHT  = 1572864;                 // 2*256*1024 = 524288
static const size_t OFF_XPART = OFF_WHHT + 524288;       // 512*32*2048 = 33554432
static const size_t OFF_HCAT  = OFF_XPART + 33554432;    // 32*512*512 = 8388608
// total = 44,040,192 floats = 176,160,768 bytes

// ---------------------------------------------------------------- prep ------
__global__ void prep(const float* __restrict__ wihf, const float* __restrict__ wihb,
                     const float* __restrict__ whhf, const float* __restrict__ whhb,
                     float* __restrict__ w_ihT, float* __restrict__ w_hhT,
                     float* __restrict__ d_loss) {
  int idx = blockIdx.x * 256 + threadIdx.x;
  if (idx == 0) d_loss[0] = 0.f;
  if (idx < 1572864) {
    int k = idx >> 11;      // row of w_ihT (k in 0..767)
    int c = idx & 2047;     // col: d*1024 + j
    int d = c >> 10;
    int j = c & 1023;
    w_ihT[idx] = d ? wihb[j * ND + k] : wihf[j * ND + k];
  } else {
    int i2 = idx - 1572864; // < 524288, layout [(d*256+k)*1024 + j]
    int d = i2 >> 18;
    int r = i2 & 262143;
    int k = r >> 10;
    int j = r & 1023;
    w_hhT[i2] = d ? whhb[j * NH + k] : whhf[j * NH + k];
  }
}

// -------------------------------------------------------------- gemm_x ------
// C[r][c] = sum_k x[(b*512+t)*768+k] * w_ihT[k][c] + bias[c],  r = t*32+b
__global__ __launch_bounds__(256, 2)
void gemm_x(const float* __restrict__ x, const float* __restrict__ wT,
            const float* __restrict__ bf, const float* __restrict__ bb,
            float* __restrict__ xpart) {
  __shared__ float As[8][128];
  __shared__ float Bs[8][128];
  const int tid = threadIdx.x;
  const int tx = tid & 15, ty = tid >> 4;
  const int r0 = blockIdx.y * 128, c0 = blockIdx.x * 128;

  float acc[8][8] = {};

  const int arow = tid >> 1;        // 0..127
  const int akq  = (tid & 1) * 4;   // 0 or 4
  const int rA = r0 + arow;
  const float* aptr = x + ((size_t)((rA & 31) * NT + (rA >> 5)) * ND) + akq;
  const int bk = tid >> 5;          // 0..7
  const int bc = (tid & 31) * 4;    // 0..124
  const float* bptr = wT + (size_t)bk * NC + c0 + bc;

  for (int k0 = 0; k0 < ND; k0 += 8) {
    float4 av = *(const float4*)(aptr + k0);
    float4 bv = *(const float4*)(bptr + (size_t)k0 * NC);
    __syncthreads();
    As[akq + 0][arow] = av.x;
    As[akq + 1][arow] = av.y;
    As[akq + 2][arow] = av.z;
    As[akq + 3][arow] = av.w;
    *(float4*)&Bs[bk][bc] = bv;
    __syncthreads();
#pragma unroll
    for (int k = 0; k < 8; ++k) {
      float4 a0 = *(const float4*)&As[k][ty * 8];
      float4 a1 = *(const float4*)&As[k][ty * 8 + 4];
      float4 b0 = *(const float4*)&Bs[k][tx * 8];
      float4 b1 = *(const float4*)&Bs[k][tx * 8 + 4];
      float am[8] = {a0.x, a0.y, a0.z, a0.w, a1.x, a1.y, a1.z, a1.w};
      float bm[8] = {b0.x, b0.y, b0.z, b0.w, b1.x, b1.y, b1.z, b1.w};
#pragma unroll
      for (int i = 0; i < 8; ++i)
#pragma unroll
        for (int j = 0; j < 8; ++j) acc[i][j] += am[i] * bm[j];
    }
  }

  const int cbase = c0 + tx * 8;
  float bias[8];
#pragma unroll
  for (int j = 0; j < 8; ++j) {
    int c = cbase + j;
    bias[j] = (c < NG) ? bf[c] : bb[c - NG];
  }
#pragma unroll
  for (int i = 0; i < 8; ++i) {
    int r = r0 + ty * 8 + i;
    float4 v0 = {acc[i][0] + bias[0], acc[i][1] + bias[1],
                 acc[i][2] + bias[2], acc[i][3] + bias[3]};
    float4 v1 = {acc[i][4] + bias[4], acc[i][5] + bias[5],
                 acc[i][6] + bias[6], acc[i][7] + bias[7]};
    *(float4*)(xpart + (size_t)r * NC + cbase) = v0;
    *(float4*)(xpart + (size_t)r * NC + cbase + 4) = v1;
  }
}

// ------------------------------------------------------------ lstm_scan -----
// 64 blocks: blockIdx = d*32 + b. Thread tid owns hidden unit tid.
__global__ __launch_bounds__(256, 1)
void lstm_scan(const float* __restrict__ whhT, const float* __restrict__ xpart,
               float* __restrict__ hcat) {
  __shared__ float hS[NH];
  __shared__ float gS[NG];
  const int tid = threadIdx.x;
  const int d = blockIdx.x >> 5;
  const int b = blockIdx.x & 31;
  const float* wT = whhT + (size_t)d * (NH * NG);  // [256][1024]
  float c = 0.f;
  hS[tid] = 0.f;
  __syncthreads();
  const int j0 = tid * 4;
  for (int s = 0; s < NT; ++s) {
    const int t = d ? (NT - 1 - s) : s;
    const float* xp = xpart + ((size_t)(t * NB + b) * NC) + d * NG + j0;
    float4 acc = *(const float4*)xp;
#pragma unroll 8
    for (int k = 0; k < NH; ++k) {
      float hk = hS[k];
      float4 w = *(const float4*)(wT + (size_t)k * NG + j0);
      acc.x += hk * w.x;
      acc.y += hk * w.y;
      acc.z += hk * w.z;
      acc.w += hk * w.w;
    }
    *(float4*)&gS[j0] = acc;
    __syncthreads();
    float gi = gS[tid], gf = gS[NH + tid], gg = gS[2 * NH + tid], go = gS[3 * NH + tid];
    float ii = 1.f / (1.f + expf(-gi));
    float ff = 1.f / (1.f + expf(-gf));
    float tg = tanhf(gg);
    float oo = 1.f / (1.f + expf(-go));
    c = ff * c + ii * tg;
    float h = oo * tanhf(c);
    hS[tid] = h;
    hcat[((size_t)(b * NT + t)) * NHC + d * NH + tid] = h;
    __syncthreads();
  }
}

// ------------------------------------------------------------ emissions -----
__global__ void emissions(const float* __restrict__ hcat, const float* __restrict__ wtag,
                          const float* __restrict__ btag, float* __restrict__ em) {
  __shared__ float wS[NL * NHC];
  const int tid = threadIdx.x;
  for (int i = tid; i < NL * NHC; i += 256) wS[i] = wtag[i];
  __syncthreads();
  const int w = tid >> 6, l = tid & 63;
  const int r = blockIdx.x * 4 + w;
  const float* hp = hcat + (size_t)r * NHC;
  float acc[NL] = {};
#pragma unroll
  for (int rep = 0; rep < 8; ++rep) {
    float hv = hp[l + rep * 64];
#pragma unroll
    for (int j = 0; j < NL; ++j) acc[j] += hv * wS[j * NHC + l + rep * 64];
  }
#pragma unroll
  for (int j = 0; j < NL; ++j) {
#pragma unroll
    for (int off = 32; off; off >>= 1) acc[j] += __shfl_xor(acc[j], off, 64);
  }
  if (l == 0) {
#pragma unroll
    for (int j = 0; j < NL; ++j) em[(size_t)r * NL + j] = acc[j] + btag[j];
  }
}

// -------------------------------------------------------------- crf_fwd -----
// One wave per batch. Lanes p<36: j = p>>2 (state), q = p&3; lane covers
// prev-states {q, q+4, 8 if q==0}. Leader lane 4*j holds score[j].
__global__ void crf_fwd(const float* __restrict__ em, const int* __restrict__ mask,
                        const int* __restrict__ labels, const float* __restrict__ start,
                        const float* __restrict__ endt, const float* __restrict__ trans,
                        float* __restrict__ d_loss) {
  __shared__ float emS[NT * NL];
  __shared__ float maskS[NT];
  __shared__ int lblS[NT];
  const int b = blockIdx.x;
  const int tid = threadIdx.x;
  for (int i = tid; i < NT * NL; i += 64) emS[i] = em[(size_t)b * NT * NL + i];
  for (int i = tid; i < NT; i += 64) {
    maskS[i] = (float)mask[b * NT + i];
    int lb = labels[b * NT + i];
    lblS[i] = (lb == -100) ? 0 : lb;
  }
  __syncthreads();

  // numerator partials
  float part = 0.f, msum = 0.f;
  for (int t = tid; t < NT; t += 64) {
    msum += maskS[t];
    if (t >= 1)
      part += (trans[lblS[t - 1] * NL + lblS[t]] + emS[t * NL + lblS[t]]) * maskS[t];
  }
#pragma unroll
  for (int off = 32; off; off >>= 1) {
    part += __shfl_xor(part, off, 64);
    msum += __shfl_xor(msum, off, 64);
  }

  // denominator scan
  const int j = tid >> 2, q = tid & 3;
  const bool leader = (q == 0) && (j < NL);
  float tr0 = 0.f, tr1 = 0.f, tr2 = -1e30f;
  float score = 0.f;
  if (tid < 36) {
    tr0 = trans[q * NL + j];
    tr1 = trans[(q + 4) * NL + j];
    if (q == 0) tr2 = trans[8 * NL + j];
    if (leader) score = start[j] + emS[j];
  }
  for (int t = 1; t < NT; ++t) {
    float s0 = __shfl(score, q * 4, 64);
    float s1 = __shfl(score, (q + 4) * 4, 64);
    float s2 = __shfl(score, 32, 64);
    float v0 = s0 + tr0, v1 = s1 + tr1;
    float v2 = (q == 0) ? (s2 + tr2) : -1e30f;
    float m = fmaxf(fmaxf(v0, v1), v2);
    m = fmaxf(m, __shfl_xor(m, 1, 4));
    m = fmaxf(m, __shfl_xor(m, 2, 4));
    float e = expf(v0 - m) + expf(v1 - m) + ((q == 0) ? expf(v2 - m) : 0.f);
    e += __shfl_xor(e, 1, 4);
    e += __shfl_xor(e, 2, 4);
    if (leader) {
      float nxt = m + logf(e) + emS[t * NL + j];
      score = (maskS[t] > 0.f) ? nxt : score;
    }
  }
  // denom = LSE(score + end)
  float vs[NL];
  float mx = -1e30f;
#pragma unroll
  for (int jj = 0; jj < NL; ++jj) {
    float sj = __shfl(score, jj * 4, 64) + endt[jj];
    vs[jj] = sj;
    mx = fmaxf(mx, sj);
  }
  float se = 0.f;
#pragma unroll
  for (int jj = 0; jj < NL; ++jj) se += expf(vs[jj] - mx);
  float denom = mx + logf(se);
  if (tid == 0) {
    int li = (int)(msum - 0.5f);  // sum(mask)-1
    float num = start[lblS[0]] + emS[lblS[0]] + part + endt[lblS[li]];
    atomicAdd(d_loss, -(num - denom) * (1.f / 32.f));
  }
}

// ---------------------------------------------------------- crf_viterbi -----
__global__ void crf_viterbi(const float* __restrict__ em, const int* __restrict__ mask,
                            const float* __restrict__ start, const float* __restrict__ endt,
                            const float* __restrict__ trans, float* __restrict__ preds) {
  __shared__ float emS[NT * NL];
  __shared__ int maskS[NT];
  __shared__ short bpS[(NT - 1) * NL];
  __shared__ short tagS[NT];
  const int b = blockIdx.x;
  const int tid = threadIdx.x;
  for (int i = tid; i < NT * NL; i += 64) emS[i] = em[(size_t)b * NT * NL + i];
  for (int i = tid; i < NT; i += 64) maskS[i] = mask[b * NT + i];
  __syncthreads();

  const int j = tid >> 2, q = tid & 3;
  const bool leader = (q == 0) && (j < NL);
  float tr0 = 0.f, tr1 = 0.f, tr2 = -1e30f;
  float score = 0.f;
  if (tid < 36) {
    tr0 = trans[q * NL + j];
    tr1 = trans[(q + 4) * NL + j];
    if (q == 0) tr2 = trans[8 * NL + j];
    if (leader) score = start[j] + emS[j];
  }
  for (int t = 1; t < NT; ++t) {
    float s0 = __shfl(score, q * 4, 64);
    float s1 = __shfl(score, (q + 4) * 4, 64);
    float s2 = __shfl(score, 32, 64);
    float v0 = s0 + tr0, v1 = s1 + tr1;
    float v2 = (q == 0) ? (s2 + tr2) : -1e30f;
    // per-lane argmax, candidates in increasing prev-index order (q < q+4 < 8)
    float bv = v0;
    int bi = q;
    if (v1 > bv) { bv = v1; bi = q + 4; }
    if (q == 0 && v2 > bv) { bv = v2; bi = 8; }
    // 4-lane reduce, first-index tie-break
#pragma unroll
    for (int off = 1; off <= 2; off <<= 1) {
      float ov = __shfl_xor(bv, off, 4);
      int oi = __shfl_xor(bi, off, 4);
      if (ov > bv || (ov == bv && oi < bi)) { bv = ov; bi = oi; }
    }
    if (leader) {
      int keep = maskS[t];
      float nxt = bv + emS[t * NL + j];
      bpS[(t - 1) * NL + j] = keep ? (short)bi : (short)j;
      score = keep ? nxt : score;
    }
  }
  // final argmax (first-index)
  float fv[NL];
#pragma unroll
  for (int jj = 0; jj < NL; ++jj) fv[jj] = __shfl(score, jj * 4, 64) + endt[jj];
  if (tid == 0) {
    int last = 0;
    float bvv = fv[0];
#pragma unroll
    for (int jj = 1; jj < NL; ++jj)
      if (fv[jj] > bvv) { bvv = fv[jj]; last = jj; }
    tagS[NT - 1] = (short)last;
    for (int t = NT - 1; t >= 1; --t) tagS[t - 1] = bpS[(t - 1) * NL + tagS[t]];
  }
  __syncthreads();
  for (int i = tid; i < NT; i += 64) preds[(size_t)b * NT + i] = (float)tagS[i];
}

// ---------------------------------------------------------------------------
extern "C" void kernel_launch(void* const* d_in, const int* in_sizes, int n_in,
                              void* d_out, int out_size, void* d_ws, size_t ws_size,
                              hipStream_t stream) {
  const float* seq_out = (const float*)d_in[0];
  const int* attn = (const int*)d_in[1];
  const int* labels = (const int*)d_in[2];
  const float* w_ih_f = (const float*)d_in[3];
  const float* w_hh_f = (const float*)d_in[4];
  const float* b_f = (const float*)d_in[5];
  const float* w_ih_b = (const float*)d_in[6];
  const float* w_hh_b = (const float*)d_in[7];
  const float* b_b = (const float*)d_in[8];
  const float* w_tag = (const float*)d_in[9];
  const float* b_tag = (const float*)d_in[10];
  const float* start_t = (const float*)d_in[11];
  const float* end_t = (const float*)d_in[12];
  const float* trans = (const float*)d_in[13];
  (void)in_sizes; (void)n_in; (void)out_size; (void)ws_size;

  float* ws = (float*)d_ws;
  float* w_ihT = ws + OFF_WIHT;
  float* w_hhT = ws + OFF_WHHT;
  float* xpart = ws + OFF_XPART;
  float* hcat = ws + OFF_HCAT;

  float* em = (float*)d_out;
  float* d_loss = em + NB * NT * NL;       // 147456
  float* preds = d_loss + 1;

  prep<<<8192, 256, 0, stream>>>(w_ih_f, w_ih_b, w_hh_f, w_hh_b, w_ihT, w_hhT, d_loss);
  gemm_x<<<dim3(16, 128), 256, 0, stream>>>(seq_out, w_ihT, b_f, b_b, xpart);
  lstm_scan<<<64, 256, 0, stream>>>(w_hhT, xpart, hcat);
  emissions<<<4096, 256, 0, stream>>>(hcat, w_tag, b_tag, em);
  crf_fwd<<<32, 64, 0, stream>>>(em, attn, labels, start_t, end_t, trans, d_loss);
  crf_viterbi<<<32, 64, 0, stream>>>(em, attn, start_t, end_t, trans, preds);
}